// Round 11
// baseline (320.052 us; speedup 1.0000x reference)
//
#include <hip/hip_runtime.h>
#include <hip/hip_bf16.h>

typedef __attribute__((ext_vector_type(8))) short s16x8;
typedef __attribute__((ext_vector_type(4))) short s16x4;
typedef __attribute__((ext_vector_type(4))) float f32x4;

#define B_ 2
#define L_ 2048
#define E_ 2048
#define H_ 16
#define D_ 128

__device__ __forceinline__ float b2f(short s) {
    unsigned u = ((unsigned)(unsigned short)s) << 16;
    return __builtin_bit_cast(float, u);
}
__device__ __forceinline__ short f2b(float f) {
    unsigned u = __builtin_bit_cast(unsigned, f);
    unsigned r = u + 0x7FFFu + ((u >> 16) & 1u);
    return (short)(r >> 16);
}

__device__ __forceinline__ void lds16(const short* g, short* l) {
    __builtin_amdgcn_global_load_lds(
        (const __attribute__((address_space(1))) void*)g,
        (__attribute__((address_space(3))) void*)l, 16, 0, 0);
}

// ---------------- fp32 -> bf16 convert ----------------
__global__ __launch_bounds__(256) void cvt_kernel(const float* __restrict__ in,
                                                  short* __restrict__ out, int n4) {
    int i = blockIdx.x * 256 + threadIdx.x;
    if (i < n4) {
        float4 v = ((const float4*)in)[i];
        s16x4 o;
        o.x = f2b(v.x); o.y = f2b(v.y); o.z = f2b(v.z); o.w = f2b(v.w);
        ((s16x4*)out)[i] = o;
    }
}

// ---------------- RoPE trig table: [L][D/2] (cos, sin) ----------------
__global__ __launch_bounds__(256) void trig_kernel(float2* __restrict__ tab) {
    int i = blockIdx.x * 256 + threadIdx.x;   // L * 64 = 131072
    if (i < L_ * 64) {
        int l = i >> 6, f = i & 63;
        float inv = expf(-(float)(2 * f) * (9.210340371976184f / 128.f));
        float ang = (float)l * inv;
        tab[i] = make_float2(cosf(ang), sinf(ang));
    }
}

// ---------------- GEMM C[M,N] = A[M,K] * B[N,K]^T + bias (m97 structure + T2 swizzle) ----------------
template<int OUT_BF16>
__global__ __launch_bounds__(256, 2)
void gemm_bt(const short* __restrict__ A, const short* __restrict__ Bm,
             const float* __restrict__ bias, void* __restrict__ Cv,
             int M, int N, int K) {
    __shared__ __align__(16) short As[128 * 32];
    __shared__ __align__(16) short Bs[128 * 32];
    const int t = threadIdx.x;
    const int wid = t >> 6, lane = t & 63;
    const int fr = lane & 15, kg = lane >> 4;
    const int m0 = blockIdx.x * 128, n0 = blockIdx.y * 128;
    const int wm = (wid >> 1) * 64, wn = (wid & 1) * 64;
    f32x4 acc[4][4] = {};
    const int srow = wid * 16 + (lane >> 2);
    const int skk = ((lane & 3) ^ ((lane >> 3) & 3)) * 8;   // pre-swizzled k-col
    const int sw = kg ^ ((fr >> 1) & 3);                    // read-side slot
    const short* ga = A + (size_t)(m0 + srow) * K + skk;
    const short* gb = Bm + (size_t)(n0 + srow) * K + skk;
    short* lA0 = As + wid * 512;
    short* lA1 = As + 2048 + wid * 512;
    short* lB0 = Bs + wid * 512;
    short* lB1 = Bs + 2048 + wid * 512;

    for (int kt = 0; kt < K; kt += 32) {
        lds16(ga + kt, lA0);
        lds16(ga + kt + (size_t)64 * K, lA1);
        lds16(gb + kt, lB0);
        lds16(gb + kt + (size_t)64 * K, lB1);
        __syncthreads();
        s16x8 af[4], bf[4];
#pragma unroll
        for (int i = 0; i < 4; i++) {
            af[i] = *(const s16x8*)(As + (wm + i * 16 + fr) * 32 + sw * 8);
            bf[i] = *(const s16x8*)(Bs + (wn + i * 16 + fr) * 32 + sw * 8);
        }
#pragma unroll
        for (int mi = 0; mi < 4; mi++)
#pragma unroll
            for (int ni = 0; ni < 4; ni++)
                acc[mi][ni] = __builtin_amdgcn_mfma_f32_16x16x32_bf16(af[mi], bf[ni], acc[mi][ni], 0, 0, 0);
        __syncthreads();
    }
#pragma unroll
    for (int mi = 0; mi < 4; mi++) {
#pragma unroll
        for (int ni = 0; ni < 4; ni++) {
            int gn = n0 + wn + ni * 16 + fr;
            float bv = bias[gn];
#pragma unroll
            for (int r = 0; r < 4; r++) {
                int gm = m0 + wm + mi * 16 + kg * 4 + r;
                float v = acc[mi][ni][r] + bv;
                if (OUT_BF16)
                    ((short*)Cv)[(size_t)gm * N + gn] = f2b(v);
                else
                    ((float*)Cv)[(size_t)gm * N + gn] = v;
            }
        }
    }
}

// ---------------- rearrange qkv (B,L,3E) -> q,k (B,H,L,D) w/ RoPE; v -> (B,H,D,L) ----------------
// q is pre-scaled by 1/sqrt(D) so attn skips the per-element score scale.
__global__ __launch_bounds__(256)
void rearrange_rope(const short* __restrict__ qkv, const float2* __restrict__ trig,
                    short* __restrict__ q, short* __restrict__ k, short* __restrict__ vt) {
    __shared__ __align__(16) short vtile[64 * 128];
    const int t = threadIdx.x;
    const int bid = blockIdx.x;      // (bh)*32 + ltile
    const int l0 = (bid & 31) << 6;
    const int bh = bid >> 5;
    const int b = bh >> 4, h = bh & 15;
    const int rr = t >> 4, c16 = t & 15;

#pragma unroll
    for (int part = 0; part < 2; part++) {
        short* dst = part ? k : q;
        const float qs = part ? 1.0f : 0.08838834764831845f;
#pragma unroll
        for (int rb = 0; rb < 4; rb++) {
            int l = l0 + rb * 16 + rr;
            const short* p = qkv + ((size_t)(b * L_ + l)) * (3 * E_) + part * E_ + h * D_ + c16 * 8;
            s16x8 v = *(const s16x8*)p;
            float2 cs[4];
#pragma unroll
            for (int jj = 0; jj < 4; jj++) cs[jj] = trig[l * 64 + c16 * 4 + jj];
            s16x8 o;
#pragma unroll
            for (int jj = 0; jj < 4; jj++) {
                float x0 = b2f(v[2 * jj]), x1 = b2f(v[2 * jj + 1]);
                o[2 * jj]     = f2b((x0 * cs[jj].x - x1 * cs[jj].y) * qs);
                o[2 * jj + 1] = f2b((x1 * cs[jj].x + x0 * cs[jj].y) * qs);
            }
            *(s16x8*)(dst + ((size_t)bh * L_ + l) * D_ + c16 * 8) = o;
        }
    }
#pragma unroll
    for (int rb = 0; rb < 4; rb++) {
        int lr = rb * 16 + rr;
        const short* p = qkv + ((size_t)(b * L_ + l0 + lr)) * (3 * E_) + 2 * E_ + h * D_ + c16 * 8;
        s16x8 v = *(const s16x8*)p;
        int sw = ((lr & 7) ^ (lr >> 3)) << 4;
        *(s16x8*)((char*)vtile + lr * 256 + ((c16 * 16) ^ sw)) = v;
    }
    __syncthreads();
#pragma unroll
    for (int pass = 0; pass < 4; pass++) {
        int d = pass * 32 + (t >> 3);
        int lg = t & 7;
        s16x8 o;
#pragma unroll
        for (int jj = 0; jj < 8; jj++) {
            int row = lg * 8 + jj;
            int sw = ((row & 7) ^ (row >> 3)) << 4;
            o[jj] = *(const short*)((char*)vtile + row * 256 + ((d * 2) ^ sw));
        }
        *(s16x8*)(vt + ((size_t)bh * D_ + d) * L_ + l0 + lg * 8) = o;
    }
}

// ---------------- causal flash attention: 8 waves, s-split strips, uniform pairs ----------------
// Block = 512 thr (8 waves). Each 16-q-row strip is owned by a wave PAIR that
// splits the 64 kv columns in half (h = wid&1). Halves per-wave: 8 QK MFMA +
// 8 PV MFMA (chain halved), cross-half max merged via tiny LDS at the
// existing barrier. Uniform q-tile pairs (qt, 31-qt) -> 33 iters/block under
// any dispatch mapping. 2 blocks/CU = 16 waves/CU = 4 waves/SIMD (2x r10 TLP).
__global__ __launch_bounds__(512, 4)
void attn_kernel(const short* __restrict__ Q, const short* __restrict__ Kb,
                 const short* __restrict__ Vt, short* __restrict__ O) {
    __shared__ __align__(16) char smem[41472];
    short* Ks = (short*)smem;              // 16 KB  [64 s][128 d] swizzled
    short* Vs = (short*)(smem + 16384);    // 16 KB  [128 d][64 s] swizzled
    char*  Ps = smem + 32768;              //  8 KB  per-wave 1 KB [16 q][32 s]
    float* Ms = (float*)(smem + 40960);    // 512 B  [8 pairslots][16 rows]
    float* Os = (float*)smem;              // merge reuse over Ks+Vs (32 KB)

    const int t = threadIdx.x;
    const int wid = t >> 6, lane = t & 63;
    const int strip = wid >> 1, hh = wid & 1;   // strip 0..3, kv-half 0/1
    const int fr = lane & 15, kg = lane >> 4;
    const int bid = blockIdx.x;
    const int qp = bid & 15, bh = bid >> 4;     // 512 blocks: 16 pairs x 32 bh
    const int bb = bh >> 4, hd = bh & 15;
    const size_t base = (size_t)bh * (L_ * D_);

    // staging maps (512 threads, 2 x 16B each per matrix)
    const int krr = t >> 4, kcc = t & 15;   // K rows krr, krr+32
    const int vdd = t >> 3, vll = t & 7;    // V rows vdd, vdd+64

    s16x8 kreg[2], vreg[2];
#define LOADKV(s0v) {                                                          \
        kreg[0] = *(const s16x8*)(Kb + base + (size_t)((s0v) + krr) * D_ + kcc * 8);       \
        kreg[1] = *(const s16x8*)(Kb + base + (size_t)((s0v) + 32 + krr) * D_ + kcc * 8);  \
        vreg[0] = *(const s16x8*)(Vt + base + (size_t)vdd * L_ + (s0v) + vll * 8);         \
        vreg[1] = *(const s16x8*)(Vt + base + (size_t)(64 + vdd) * L_ + (s0v) + vll * 8);  \
    }
#define WRITEKV() {                                                            \
        int rw0 = krr;                                                         \
        *(s16x8*)((char*)Ks + rw0 * 256 + ((kcc * 16) ^ ((rw0 & 7) << 4))) = kreg[0]; \
        int rw1 = krr + 32;                                                    \
        *(s16x8*)((char*)Ks + rw1 * 256 + ((kcc * 16) ^ ((rw1 & 7) << 4))) = kreg[1]; \
        int dw0 = vdd;                                                         \
        *(s16x8*)((char*)Vs + dw0 * 128 + ((vll * 16) ^ ((dw0 & 7) << 4))) = vreg[0]; \
        int dw1 = vdd + 64;                                                    \
        *(s16x8*)((char*)Vs + dw1 * 128 + ((vll * 16) ^ ((dw1 & 7) << 4))) = vreg[1]; \
    }

    LOADKV(0);
    WRITEKV();
    __syncthreads();

    for (int ph = 0; ph < 2; ph++) {
        const int qt = ph ? (31 - qp) : qp;
        const int q0 = qt << 6;
        s16x8 qa[4];
        {
            const short* qptr = Q + base + (size_t)(q0 + strip * 16 + fr) * D_ + kg * 8;
#pragma unroll
            for (int ch = 0; ch < 4; ch++) qa[ch] = *(const s16x8*)(qptr + ch * 32);
        }
        f32x4 oacc[8] = {};
        float mrow[4], lrow[4];
#pragma unroll
        for (int r = 0; r < 4; r++) { mrow[r] = -1e30f; lrow[r] = 0.f; }

        const int ntile = qt + 1;
        for (int ti = 0; ti < ntile; ti++) {
            const int s0 = ti << 6;
            const int nxt = (ti + 1 < ntile) ? (s0 + 64) : (ph == 0 ? 0 : -1);
            if (nxt >= 0) LOADKV(nxt);
            // QK^T: S (16q x 32s own half) per wave
            f32x4 sacc[2] = {};
            __builtin_amdgcn_s_setprio(1);
#pragma unroll
            for (int ch = 0; ch < 4; ch++) {
#pragma unroll
                for (int ni = 0; ni < 2; ni++) {
                    int row = hh * 32 + ni * 16 + fr;
                    s16x8 kf = *(const s16x8*)((char*)Ks + row * 256 +
                                               ((ch * 64 + kg * 16) ^ ((row & 7) << 4)));
                    sacc[ni] = __builtin_amdgcn_mfma_f32_16x16x32_bf16(qa[ch], kf, sacc[ni], 0, 0, 0);
                }
            }
            __builtin_amdgcn_s_setprio(0);
            // causal mask + own-half row max
            const bool diag = (s0 == q0);
            float sv[2][4];
            float tm[4] = {-1e30f, -1e30f, -1e30f, -1e30f};
#pragma unroll
            for (int ni = 0; ni < 2; ni++)
#pragma unroll
                for (int r = 0; r < 4; r++) {
                    float x = sacc[ni][r];
                    if (diag && (hh * 32 + ni * 16 + fr > strip * 16 + kg * 4 + r)) x = -1e30f;
                    sv[ni][r] = x;
                    tm[r] = fmaxf(tm[r], x);
                }
#pragma unroll
            for (int r = 0; r < 4; r++)
#pragma unroll
                for (int off = 1; off < 16; off <<= 1)
                    tm[r] = fmaxf(tm[r], __shfl_xor(tm[r], off));
            // cross-half max merge (partner wave) via tiny LDS
            if (fr == 0) {
#pragma unroll
                for (int r = 0; r < 4; r++)
                    Ms[(strip * 2 + hh) * 16 + kg * 4 + r] = tm[r];
            }
            __syncthreads();
#pragma unroll
            for (int r = 0; r < 4; r++)
                tm[r] = fmaxf(tm[r], Ms[(strip * 2 + (1 - hh)) * 16 + kg * 4 + r]);
            // defer-max (T13): both halves see identical tm -> identical branch
            int ok = 1;
#pragma unroll
            for (int r = 0; r < 4; r++) ok &= (tm[r] <= mrow[r] + 8.0f);
            if (!__all(ok)) {
#pragma unroll
                for (int r = 0; r < 4; r++) {
                    float mnew = fmaxf(mrow[r], tm[r]);
                    float sc = __expf(mrow[r] - mnew);
                    mrow[r] = mnew;
                    lrow[r] *= sc;
#pragma unroll
                    for (int di = 0; di < 8; di++) oacc[di][r] *= sc;
                }
            }
            // P = exp(S - m); per-lane partial row-sums (own half)
#pragma unroll
            for (int ni = 0; ni < 2; ni++)
#pragma unroll
                for (int r = 0; r < 4; r++) {
                    float p = __expf(sv[ni][r] - mrow[r]);
                    sv[ni][r] = p;
                    lrow[r] += p;
                }
            // write P to own 1KB slot: elem P[q][s] at byte q*64 + ((s*2)^((q&3)<<4))
#pragma unroll
            for (int ni = 0; ni < 2; ni++)
#pragma unroll
                for (int r = 0; r < 4; r++) {
                    int qq = kg * 4 + r;
                    *(short*)(Ps + wid * 1024 + qq * 64 +
                              ((ni * 32 + fr * 2) ^ ((qq & 3) << 4))) = f2b(sv[ni][r]);
                }
            // PV: O (16q x 128d) += P(16x32 own half) * V(32x128 own half)
            s16x8 pa = *(const s16x8*)(Ps + wid * 1024 + fr * 64 +
                                       ((kg * 16) ^ ((fr & 3) << 4)));
            __builtin_amdgcn_s_setprio(1);
#pragma unroll
            for (int di = 0; di < 8; di++) {
                int row = di * 16 + fr;
                s16x8 vf = *(const s16x8*)((char*)Vs + row * 128 +
                                           ((hh * 64 + kg * 16) ^ ((row & 7) << 4)));
                oacc[di] = __builtin_amdgcn_mfma_f32_16x16x32_bf16(pa, vf, oacc[di], 0, 0, 0);
            }
            __builtin_amdgcn_s_setprio(0);
            __syncthreads();               // all waves done reading Ks/Vs/Ms
            if (ti + 1 < ntile) {          // in-loop K/V refresh
                WRITEKV();
                __syncthreads();
            }
        }
        // own-half l reduce
#pragma unroll
        for (int r = 0; r < 4; r++)
#pragma unroll
            for (int off = 1; off < 16; off <<= 1)
                lrow[r] += __shfl_xor(lrow[r], off);
        // cross-half O/l merge: Ks/Vs dead for this phase -> reuse as f32 Os
        if (hh == 1) {
#pragma unroll
            for (int r = 0; r < 4; r++) {
                int qq = kg * 4 + r;
#pragma unroll
                for (int di = 0; di < 8; di++)
                    Os[strip * 2048 + qq * 128 + di * 16 + fr] = oacc[di][r];
                if (fr == 0) Ms[(strip * 2 + 1) * 16 + qq] = lrow[r];
            }
        }
        __syncthreads();
        if (hh == 0) {
#pragma unroll
            for (int r = 0; r < 4; r++) {
                int qq = kg * 4 + r;
                float l = lrow[r] + Ms[(strip * 2 + 1) * 16 + qq];
                float rl = 1.f / l;
                int qg = q0 + strip * 16 + qq;
                size_t orow = (size_t)(bb * L_ + qg) * E_ + hd * D_;
#pragma unroll
                for (int di = 0; di < 8; di++) {
                    float v = oacc[di][r] + Os[strip * 2048 + qq * 128 + di * 16 + fr];
                    O[orow + di * 16 + fr] = f2b(v * rl);
                }
            }
        }
        __syncthreads();
        if (ph == 0) {                     // tile 0 (prefetched in regs) for phase 1
            WRITEKV();
            __syncthreads();
        }
    }
#undef LOADKV
#undef WRITEKV
}

extern "C" void kernel_launch(void* const* d_in, const int* in_sizes, int n_in,
                              void* d_out, int out_size, void* d_ws, size_t ws_size,
                              hipStream_t stream) {
    const float* x     = (const float*)d_in[0];
    const float* wqkv  = (const float*)d_in[1];
    const float* bqkv  = (const float*)d_in[2];
    const float* wout  = (const float*)d_in[3];
    const float* bout  = (const float*)d_in[4];
    float* out = (float*)d_out;
    char* ws = (char*)d_ws;

    const size_t SZ_XB    = (size_t)4096 * 2048 * 2;
    const size_t SZ_WQKV  = (size_t)6144 * 2048 * 2;
    const size_t SZ_WOUT  = (size_t)2048 * 2048 * 2;
    const size_t SZ_QKV   = (size_t)4096 * 6144 * 2;
    const size_t SZ_HLD   = (size_t)32 * 2048 * 128 * 2;
    short* xb    = (short*)(ws);
    short* wqkvb = (short*)(ws + SZ_XB);
    short* woutb = (short*)(ws + SZ_XB + SZ_WQKV);
    short* qkvb  = (short*)(ws + SZ_XB + SZ_WQKV + SZ_WOUT);
    short* qb    = (short*)(ws + SZ_XB + SZ_WQKV + SZ_WOUT + SZ_QKV);
    short* kb    = (short*)(ws + SZ_XB + SZ_WQKV + SZ_WOUT + SZ_QKV + SZ_HLD);
    short* vtb   = (short*)(ws + SZ_XB + SZ_WQKV + SZ_WOUT + SZ_QKV + 2 * SZ_HLD);
    float2* trig = (float2*)(ws + SZ_XB + SZ_WQKV + SZ_WOUT + SZ_QKV + 3 * SZ_HLD);
    short* ob    = xb;  // alias: xb dead after GEMM1
    const size_t NEEDED = SZ_XB + SZ_WQKV + SZ_WOUT + SZ_QKV + 3 * SZ_HLD + (size_t)L_ * 64 * 8;
    if (ws_size < NEEDED) return;

    cvt_kernel<<<8192, 256, 0, stream>>>(x, xb, 2097152);
    cvt_kernel<<<12288, 256, 0, stream>>>(wqkv, wqkvb, 3145728);
    cvt_kernel<<<4096, 256, 0, stream>>>(wout, woutb, 1048576);
    trig_kernel<<<512, 256, 0, stream>>>(trig);

    gemm_bt<1><<<dim3(32, 48), 256, 0, stream>>>(xb, wqkvb, bqkv, (void*)qkvb, 4096, 6144, 2048);
    rearrange_rope<<<1024, 256, 0, stream>>>(qkvb, trig, qb, kb, vtb);
    attn_kernel<<<512, 512, 0, stream>>>(qb, kb, vtb, ob);
    gemm_bt<0><<<dim3(32, 16), 256, 0, stream>>>(ob, woutb, bout, (void*)out, 4096, 2048, 2048);
}